// Round 8
// baseline (515.799 us; speedup 1.0000x reference)
//
#include <hip/hip_runtime.h>

#define IN_FEAT 512
#define HID 16
#define NC 7
#define NXCD 8

typedef int iv4 __attribute__((ext_vector_type(4)));  // native vector: nt-load OK

// ------------------------------------------------- degree histogram (int) ---
__global__ void k_count(const iv4* __restrict__ dst4, const int* __restrict__ dst,
                        int* __restrict__ deg, int E) {
    int j = blockIdx.x * blockDim.x + threadIdx.x;
    int E4 = E >> 2;
    if (j < E4) {
        iv4 d = __builtin_nontemporal_load(dst4 + j);
        atomicAdd(&deg[d.x], 1);
        atomicAdd(&deg[d.y], 1);
        atomicAdd(&deg[d.z], 1);
        atomicAdd(&deg[d.w], 1);
    }
    if (j == 0) {
        for (int e = E & ~3; e < E; ++e) atomicAdd(&deg[dst[e]], 1);
    }
}

// --------------------- 3-phase exclusive scan (+dinv fused into phase A) ----
__global__ __launch_bounds__(1024) void k_scanA(const int* __restrict__ deg,
                                                int* __restrict__ off,
                                                float* __restrict__ dinv,
                                                int* __restrict__ btot, int n) {
    __shared__ int wsum[16];
    int tid = threadIdx.x, lane = tid & 63, wid = tid >> 6;
    int i = blockIdx.x * 1024 + tid;
    int v = (i < n) ? deg[i] : 0;
    int incl = v;
#pragma unroll
    for (int o = 1; o < 64; o <<= 1) {
        int t = __shfl_up(incl, o, 64);
        if (lane >= o) incl += t;
    }
    if (lane == 63) wsum[wid] = incl;
    __syncthreads();
    int wpre = 0;
    for (int k = 0; k < wid; ++k) wpre += wsum[k];
    int ex = wpre + incl - v;
    if (i < n) {
        off[i] = ex;                         // local (no inter-block carry yet)
        dinv[i] = rsqrtf((float)v + 1.0f);   // +1 = self-loop
    }
    if (tid == 1023) btot[blockIdx.x] = ex + v;  // block total
}

__global__ __launch_bounds__(128) void k_scanB(const int* __restrict__ btot,
                                               int* __restrict__ bcar, int nb) {
    __shared__ int wsum[2];
    int tid = threadIdx.x, lane = tid & 63, wid = tid >> 6;
    int v = (tid < nb) ? btot[tid] : 0;
    int incl = v;
#pragma unroll
    for (int o = 1; o < 64; o <<= 1) {
        int t = __shfl_up(incl, o, 64);
        if (lane >= o) incl += t;
    }
    if (lane == 63) wsum[wid] = incl;
    __syncthreads();
    int wpre = (wid == 1) ? wsum[0] : 0;
    if (tid < nb) bcar[tid] = wpre + incl - v;
}

__global__ __launch_bounds__(1024) void k_scanC(int* __restrict__ off,
                                                const int* __restrict__ bcar,
                                                int* __restrict__ cur, int n, int E) {
    int i = blockIdx.x * 1024 + threadIdx.x;
    if (i < n) {
        int o = off[i] + bcar[blockIdx.x];
        off[i] = o;
        cur[i] = o;
    }
    if (i == 0) off[n] = E;
}

// ----------------- scatter src into CSR, TRUE XCD-affine via HW_REG_XCC_ID --
// R3-R7's blockIdx&7 affinity never dropped WRITE_SIZE (132MB for 12.8MB
// payload): the blockIdx->XCD round-robin assumption is wrong. Here each
// block reads its REAL XCD id and pops a chunk from that XCD's queue, so a
// CSR range is written by exactly one XCD -> lines fill in its L2 before
// writeback. Work-stealing over the 8 queues guarantees full coverage
// regardless of the dispatch mapping (correctness never depends on it).
__global__ void k_scatter(const iv4* __restrict__ src4, const iv4* __restrict__ dst4,
                          const int* __restrict__ src, const int* __restrict__ dst,
                          int* __restrict__ cur, int* __restrict__ csr_src,
                          int* __restrict__ q, int nchunk, int E, int n) {
    __shared__ int s_item;
    unsigned xcc;
    asm volatile("s_getreg_b32 %0, hwreg(HW_REG_XCC_ID)" : "=s"(xcc));
    xcc &= (NXCD - 1);
    int rsz = (n + NXCD - 1) / NXCD;
    int E4 = E >> 2;

    for (int a = 0; a < NXCD; ++a) {
        int r = (xcc + a) & (NXCD - 1);
        if (threadIdx.x == 0) s_item = atomicAdd(&q[r], 1);
        __syncthreads();
        int chunk = s_item;
        __syncthreads();
        if (chunk >= nchunk) continue;  // queue r drained; try next (steal)

        int lo = r * rsz;
        int hi = min(n, lo + rsz);
        int base = chunk * 1024 + threadIdx.x;  // iv4 index: 256 thr * 4 batches

        iv4 dv[4], sv[4];
        bool ok[4];
#pragma unroll
        for (int i = 0; i < 4; ++i) {
            int j = base + i * 256;
            ok[i] = (j < E4);
            if (ok[i]) {
                dv[i] = __builtin_nontemporal_load(dst4 + j);
                sv[i] = __builtin_nontemporal_load(src4 + j);
            }
        }
#pragma unroll
        for (int i = 0; i < 4; ++i) {
            if (!ok[i]) continue;
            iv4 d = dv[i], s = sv[i];
            if (d.x >= lo && d.x < hi) { int p = atomicAdd(&cur[d.x], 1); csr_src[p] = s.x; }
            if (d.y >= lo && d.y < hi) { int p = atomicAdd(&cur[d.y], 1); csr_src[p] = s.y; }
            if (d.z >= lo && d.z < hi) { int p = atomicAdd(&cur[d.z], 1); csr_src[p] = s.z; }
            if (d.w >= lo && d.w < hi) { int p = atomicAdd(&cur[d.w], 1); csr_src[p] = s.w; }
        }
        if (chunk == 0) {  // scalar tail (E % 4 edges) for this range
            for (int e = (E & ~3) + (int)threadIdx.x; e < E; e += 256) {
                int d = dst[e];
                if (d >= lo && d < hi) { int p = atomicAdd(&cur[d], 1); csr_src[p] = src[e]; }
            }
        }
        return;  // one item per block
    }
}

// ------------------------------------------------------- layer 1: x @ W1 ----
// One thread per row; W indices wave-uniform -> scalar-pipe s_loads.
__global__ void k_gemm1(const float* __restrict__ x, const float* __restrict__ W,
                        float* __restrict__ h1, int n) {
    int row = blockIdx.x * blockDim.x + threadIdx.x;
    if (row >= n) return;
    const float4* xr = reinterpret_cast<const float4*>(x + (size_t)row * IN_FEAT);
    float acc[HID];
#pragma unroll
    for (int c = 0; c < HID; ++c) acc[c] = 0.0f;
#pragma unroll 2
    for (int kt = 0; kt < IN_FEAT / 4; ++kt) {
        float4 xv = xr[kt];
        const float* wk = W + (size_t)kt * 4 * HID;
#pragma unroll
        for (int c = 0; c < HID; ++c) acc[c] = fmaf(xv.x, wk[c], acc[c]);
#pragma unroll
        for (int c = 0; c < HID; ++c) acc[c] = fmaf(xv.y, wk[HID + c], acc[c]);
#pragma unroll
        for (int c = 0; c < HID; ++c) acc[c] = fmaf(xv.z, wk[2 * HID + c], acc[c]);
#pragma unroll
        for (int c = 0; c < HID; ++c) acc[c] = fmaf(xv.w, wk[3 * HID + c], acc[c]);
    }
    float4* hp = reinterpret_cast<float4*>(h1 + (size_t)row * HID);
#pragma unroll
    for (int j = 0; j < 4; ++j)
        hp[j] = make_float4(acc[4 * j], acc[4 * j + 1], acc[4 * j + 2], acc[4 * j + 3]);
}

// ------------------- gather layer 1 + bias + relu + @W2 (fused, 4 lanes/v) --
__global__ void k_gather1(const float* __restrict__ h1, const int* __restrict__ csr_src,
                          const int* __restrict__ off, const float* __restrict__ dinv,
                          const float* __restrict__ b1, const float* __restrict__ W2,
                          float* __restrict__ h2, int n) {
    int t = blockIdx.x * blockDim.x + threadIdx.x;
    int v = t >> 2, part = t & 3;
    if (v >= n) return;
    float di = dinv[v];
    float4 hv = reinterpret_cast<const float4*>(h1 + (size_t)v * HID)[part];
    float dw = di * di;
    float4 acc = make_float4(hv.x * dw, hv.y * dw, hv.z * dw, hv.w * dw);
    int beg = off[v], end = off[v + 1];
    for (int i = beg; i < end; ++i) {
        int s = csr_src[i];  // cached: consecutive iters reuse the line
        float w = dinv[s] * di;
        float4 hs = reinterpret_cast<const float4*>(h1 + (size_t)s * HID)[part];
        acc.x = fmaf(hs.x, w, acc.x);
        acc.y = fmaf(hs.y, w, acc.y);
        acc.z = fmaf(hs.z, w, acc.z);
        acc.w = fmaf(hs.w, w, acc.w);
    }
    float tt[4];
    tt[0] = fmaxf(acc.x + b1[part * 4 + 0], 0.0f);
    tt[1] = fmaxf(acc.y + b1[part * 4 + 1], 0.0f);
    tt[2] = fmaxf(acc.z + b1[part * 4 + 2], 0.0f);
    tt[3] = fmaxf(acc.w + b1[part * 4 + 3], 0.0f);
    float o[NC];
#pragma unroll
    for (int c = 0; c < NC; ++c) o[c] = 0.0f;
#pragma unroll
    for (int j = 0; j < 4; ++j) {
        int k = part * 4 + j;
#pragma unroll
        for (int c = 0; c < NC; ++c) o[c] = fmaf(tt[j], W2[k * NC + c], o[c]);
    }
#pragma unroll
    for (int c = 0; c < NC; ++c) {
        o[c] += __shfl_xor(o[c], 1);
        o[c] += __shfl_xor(o[c], 2);
    }
    float4* hp = reinterpret_cast<float4*>(h2 + (size_t)v * 8);
    if (part == 0) hp[0] = make_float4(o[0], o[1], o[2], o[3]);
    if (part == 1) hp[1] = make_float4(o[4], o[5], o[6], 0.0f);
}

// ------------------- gather layer 2 + bias + log_softmax (fused, 1 th/v) ----
__global__ void k_gather2(const float* __restrict__ h2, const int* __restrict__ csr_src,
                          const int* __restrict__ off, const float* __restrict__ dinv,
                          const float* __restrict__ b2, float* __restrict__ out, int n) {
    int v = blockIdx.x * blockDim.x + threadIdx.x;
    if (v >= n) return;
    float di = dinv[v];
    float dw = di * di;
    const float4* hr = reinterpret_cast<const float4*>(h2 + (size_t)v * 8);
    float4 s0 = hr[0], s1 = hr[1];
    float4 a0 = make_float4(s0.x * dw, s0.y * dw, s0.z * dw, s0.w * dw);
    float4 a1 = make_float4(s1.x * dw, s1.y * dw, s1.z * dw, 0.0f);
    int beg = off[v], end = off[v + 1];
    for (int i = beg; i < end; ++i) {
        int s = csr_src[i];  // cached
        float w = dinv[s] * di;
        const float4* hs = reinterpret_cast<const float4*>(h2 + (size_t)s * 8);
        float4 v0 = hs[0], v1 = hs[1];
        a0.x = fmaf(v0.x, w, a0.x);
        a0.y = fmaf(v0.y, w, a0.y);
        a0.z = fmaf(v0.z, w, a0.z);
        a0.w = fmaf(v0.w, w, a0.w);
        a1.x = fmaf(v1.x, w, a1.x);
        a1.y = fmaf(v1.y, w, a1.y);
        a1.z = fmaf(v1.z, w, a1.z);
    }
    float z[NC];
    z[0] = a0.x + b2[0]; z[1] = a0.y + b2[1]; z[2] = a0.z + b2[2]; z[3] = a0.w + b2[3];
    z[4] = a1.x + b2[4]; z[5] = a1.y + b2[5]; z[6] = a1.z + b2[6];
    float m = z[0];
#pragma unroll
    for (int c = 1; c < NC; ++c) m = fmaxf(m, z[c]);
    float sum = 0.0f;
#pragma unroll
    for (int c = 0; c < NC; ++c) sum += expf(z[c] - m);
    float lse = logf(sum) + m;
#pragma unroll
    for (int c = 0; c < NC; ++c) out[(size_t)v * NC + c] = z[c] - lse;
}

// -----------------------------------------------------------------------------
extern "C" void kernel_launch(void* const* d_in, const int* in_sizes, int n_in,
                              void* d_out, int out_size, void* d_ws, size_t ws_size,
                              hipStream_t stream) {
    const float* x  = (const float*)d_in[0];
    const int*   ei = (const int*)d_in[1];
    const float* W1 = (const float*)d_in[2];
    const float* b1 = (const float*)d_in[3];
    const float* W2 = (const float*)d_in[4];
    const float* b2 = (const float*)d_in[5];

    int n = in_sizes[0] / IN_FEAT;
    int E = in_sizes[1] / 2;
    const int* src = ei;
    const int* dst = ei + E;
    const iv4* src4 = (const iv4*)src;
    const iv4* dst4 = (const iv4*)dst;

    // workspace layout (16B-aligned chunks first)
    char* p = (char*)d_ws;
    float* h1      = (float*)p;                 p += (size_t)HID * n * sizeof(float); // 6.4 MB
    float* h2      = (float*)p;                 p += (size_t)8 * n * sizeof(float);   // 3.2 MB
    int*   csr_src = (int*)p;                   p += (size_t)E * sizeof(int);         // 12.8 MB
    int*   deg     = (int*)p;                   p += (size_t)n * sizeof(int);
    int*   q       = (int*)p;                   p += (size_t)NXCD * sizeof(int);      // scatter queues
    int*   off     = (int*)p;                   p += (size_t)(n + 1) * sizeof(int);
    int*   cur     = (int*)p;                   p += (size_t)n * sizeof(int);
    float* dinv    = (float*)p;                 p += (size_t)n * sizeof(float);
    int*   btot    = (int*)p;                   p += (size_t)128 * sizeof(int);
    int*   bcar    = (int*)p;                   p += (size_t)128 * sizeof(int);

    const int tb = 256;
    int E4 = E >> 2;
    int gE4 = (E4 + tb - 1) / tb;
    int gN = (n + tb - 1) / tb;
    int gN4 = (4 * n + tb - 1) / tb;
    int nb = (n + 1023) / 1024;                       // scan blocks (<=128)
    int nchunk = (E4 + 1023) / 1024;                  // scatter chunks (4096 edges each)

    hipMemsetAsync(deg, 0, ((size_t)n + NXCD) * sizeof(int), stream);  // deg + q
    k_count  <<<gE4, tb, 0, stream>>>(dst4, dst, deg, E);
    k_scanA  <<<nb, 1024, 0, stream>>>(deg, off, dinv, btot, n);
    k_scanB  <<<1, 128, 0, stream>>>(btot, bcar, nb);
    k_scanC  <<<nb, 1024, 0, stream>>>(off, bcar, cur, n, E);
    k_scatter<<<nchunk * NXCD, tb, 0, stream>>>(src4, dst4, src, dst, cur, csr_src,
                                                q, nchunk, E, n);
    k_gemm1  <<<gN,  tb, 0, stream>>>(x, W1, h1, n);
    k_gather1<<<gN4, tb, 0, stream>>>(h1, csr_src, off, dinv, b1, W2, h2, n);
    k_gather2<<<gN,  tb, 0, stream>>>(h2, csr_src, off, dinv, b2, (float*)d_out, n);
}

// Round 9
// 449.128 us; speedup vs baseline: 1.1484x; 1.1484x over previous
//
#include <hip/hip_runtime.h>

#define IN_FEAT 512
#define HID 16
#define NC 7

#define NPB   128          // nodes per bucket
#define NPB_SH 7
#define NBMAX 1024         // max buckets (n<=131072)
#define CAP   12288        // pass-2 LDS stage capacity (48KB)
#define P1_EDGES 8192      // edges per pass-1 block
#define P1_EPT   32        // edges per thread (256 thr)

typedef int iv4 __attribute__((ext_vector_type(4)));

// ------------------------------------------------- degree histogram (int) ---
__global__ void k_count(const iv4* __restrict__ dst4, const int* __restrict__ dst,
                        int* __restrict__ deg, int E) {
    int j = blockIdx.x * blockDim.x + threadIdx.x;
    int E4 = E >> 2;
    if (j < E4) {
        iv4 d = __builtin_nontemporal_load(dst4 + j);
        atomicAdd(&deg[d.x], 1);
        atomicAdd(&deg[d.y], 1);
        atomicAdd(&deg[d.z], 1);
        atomicAdd(&deg[d.w], 1);
    }
    if (j == 0) {
        for (int e = E & ~3; e < E; ++e) atomicAdd(&deg[dst[e]], 1);
    }
}

// --------------------- 3-phase exclusive scan (+dinv fused into phase A) ----
__global__ __launch_bounds__(1024) void k_scanA(const int* __restrict__ deg,
                                                int* __restrict__ off,
                                                float* __restrict__ dinv,
                                                int* __restrict__ btot, int n) {
    __shared__ int wsum[16];
    int tid = threadIdx.x, lane = tid & 63, wid = tid >> 6;
    int i = blockIdx.x * 1024 + tid;
    int v = (i < n) ? deg[i] : 0;
    int incl = v;
#pragma unroll
    for (int o = 1; o < 64; o <<= 1) {
        int t = __shfl_up(incl, o, 64);
        if (lane >= o) incl += t;
    }
    if (lane == 63) wsum[wid] = incl;
    __syncthreads();
    int wpre = 0;
    for (int k = 0; k < wid; ++k) wpre += wsum[k];
    int ex = wpre + incl - v;
    if (i < n) {
        off[i] = ex;
        dinv[i] = rsqrtf((float)v + 1.0f);  // +1 = self-loop
    }
    if (tid == 1023) btot[blockIdx.x] = ex + v;
}

__global__ __launch_bounds__(128) void k_scanB(const int* __restrict__ btot,
                                               int* __restrict__ bcar, int nb) {
    __shared__ int wsum[2];
    int tid = threadIdx.x, lane = tid & 63, wid = tid >> 6;
    int v = (tid < nb) ? btot[tid] : 0;
    int incl = v;
#pragma unroll
    for (int o = 1; o < 64; o <<= 1) {
        int t = __shfl_up(incl, o, 64);
        if (lane >= o) incl += t;
    }
    if (lane == 63) wsum[wid] = incl;
    __syncthreads();
    int wpre = (wid == 1) ? wsum[0] : 0;
    if (tid < nb) bcar[tid] = wpre + incl - v;
}

__global__ __launch_bounds__(1024) void k_scanC(int* __restrict__ off,
                                                const int* __restrict__ bcar,
                                                int n, int E) {
    int i = blockIdx.x * 1024 + threadIdx.x;
    if (i < n) off[i] += bcar[blockIdx.x];
    if (i == 0) off[n] = E;
}

// ------------------- pass 1: bin edges by dst-bucket (block-exclusive segs) --
// Per block: count bucket occupancy in LDS, reserve one contiguous sub-segment
// per (block,bucket) with a single returning atomic, then write (src, dst&127)
// into reserved slots. Writes are block-exclusive runs -> bounded write amp,
// and only ~306K returning atomics total (vs 3.2M in the old scatter).
__global__ __launch_bounds__(256) void k_bin(const int* __restrict__ src,
                                             const int* __restrict__ dst,
                                             const int* __restrict__ off,
                                             int* __restrict__ gcur,
                                             int* binned_src,            // = csr region
                                             unsigned char* __restrict__ binned_dl,
                                             int E, int NB) {
    __shared__ int cnt[NBMAX];
    __shared__ int sbase[NBMAX];
    __shared__ int lcur[NBMAX];
    __shared__ int bboff[NBMAX];
    int tid = threadIdx.x;
    for (int b = tid; b < NB; b += 256) {
        cnt[b] = 0;
        lcur[b] = 0;
        bboff[b] = off[b << NPB_SH];
    }
    __syncthreads();

    int base = blockIdx.x * P1_EDGES + tid;
    int d[P1_EPT];
#pragma unroll
    for (int i = 0; i < P1_EPT; ++i) {
        int e = base + i * 256;
        d[i] = (e < E) ? dst[e] : -1;
    }
#pragma unroll
    for (int i = 0; i < P1_EPT; ++i) {
        if (d[i] >= 0) atomicAdd(&cnt[d[i] >> NPB_SH], 1);
    }
    __syncthreads();
    for (int b = tid; b < NB; b += 256) {
        int c = cnt[b];
        sbase[b] = c ? atomicAdd(&gcur[b], c) : 0;
    }
    __syncthreads();
#pragma unroll
    for (int i = 0; i < P1_EPT; ++i) {
        if (d[i] < 0) continue;
        int e = base + i * 256;
        int s = src[e];
        int b = d[i] >> NPB_SH;
        int lp = atomicAdd(&lcur[b], 1);
        int idx = bboff[b] + sbase[b] + lp;
        binned_src[idx] = s;
        binned_dl[idx] = (unsigned char)(d[i] & (NPB - 1));
    }
}

// ---------------- pass 2: in-bucket sort to final CSR order, in place --------
// One block per bucket. Read the bucket's binned entries (coalesced), place
// into LDS stage at final node-order positions via LDS atomics on 128 node
// cursors, then write out fully coalesced. In-place over the csr region:
// all reads happen before the post-barrier writes.
__global__ __launch_bounds__(256) void k_sort(int* csr_src,               // in: binned, out: sorted
                                              const unsigned char* __restrict__ binned_dl,
                                              const int* __restrict__ off,
                                              const int* __restrict__ src,
                                              const int* __restrict__ dst,
                                              int n, int E) {
    __shared__ int loff[NPB + 1];
    __shared__ int lcur[NPB];
    __shared__ int stage[CAP];
    int b = blockIdx.x;
    int lo = b << NPB_SH;
    int nn = min(NPB, n - lo);
    int tid = threadIdx.x;
    if (tid <= nn) loff[tid] = off[lo + tid];
    if (tid < nn) lcur[tid] = 0;
    __syncthreads();
    int seg_base = loff[0];
    int seg = loff[nn] - seg_base;

    if (seg <= CAP) {
        for (int k = tid; k < seg; k += 256) {
            int s = csr_src[seg_base + k];
            int dl = binned_dl[seg_base + k];
            int p = (loff[dl] - seg_base) + atomicAdd(&lcur[dl], 1);
            stage[p] = s;
        }
        __syncthreads();
        for (int k = tid; k < seg; k += 256) csr_src[seg_base + k] = stage[k];
    } else {
        // statistically impossible for uniform dst; correct fallback from raw edges
        for (int e = tid; e < E; e += 256) {
            int dd = dst[e];
            if ((dd >> NPB_SH) == b) {
                int dl = dd & (NPB - 1);
                int p = loff[dl] + atomicAdd(&lcur[dl], 1);
                csr_src[p] = src[e];
            }
        }
    }
}

// ------------------------------------------------------- layer 1: x @ W1 ----
// One thread per row; W indices wave-uniform -> scalar-pipe s_loads.
__global__ void k_gemm1(const float* __restrict__ x, const float* __restrict__ W,
                        float* __restrict__ h1, int n) {
    int row = blockIdx.x * blockDim.x + threadIdx.x;
    if (row >= n) return;
    const float4* xr = reinterpret_cast<const float4*>(x + (size_t)row * IN_FEAT);
    float acc[HID];
#pragma unroll
    for (int c = 0; c < HID; ++c) acc[c] = 0.0f;
#pragma unroll 2
    for (int kt = 0; kt < IN_FEAT / 4; ++kt) {
        float4 xv = xr[kt];
        const float* wk = W + (size_t)kt * 4 * HID;
#pragma unroll
        for (int c = 0; c < HID; ++c) acc[c] = fmaf(xv.x, wk[c], acc[c]);
#pragma unroll
        for (int c = 0; c < HID; ++c) acc[c] = fmaf(xv.y, wk[HID + c], acc[c]);
#pragma unroll
        for (int c = 0; c < HID; ++c) acc[c] = fmaf(xv.z, wk[2 * HID + c], acc[c]);
#pragma unroll
        for (int c = 0; c < HID; ++c) acc[c] = fmaf(xv.w, wk[3 * HID + c], acc[c]);
    }
    float4* hp = reinterpret_cast<float4*>(h1 + (size_t)row * HID);
#pragma unroll
    for (int j = 0; j < 4; ++j)
        hp[j] = make_float4(acc[4 * j], acc[4 * j + 1], acc[4 * j + 2], acc[4 * j + 3]);
}

// ------------------- gather layer 1 + bias + relu + @W2 (fused, 4 lanes/v) --
__global__ void k_gather1(const float* __restrict__ h1, const int* __restrict__ csr_src,
                          const int* __restrict__ off, const float* __restrict__ dinv,
                          const float* __restrict__ b1, const float* __restrict__ W2,
                          float* __restrict__ h2, int n) {
    int t = blockIdx.x * blockDim.x + threadIdx.x;
    int v = t >> 2, part = t & 3;
    if (v >= n) return;
    float di = dinv[v];
    float4 hv = reinterpret_cast<const float4*>(h1 + (size_t)v * HID)[part];
    float dw = di * di;
    float4 acc = make_float4(hv.x * dw, hv.y * dw, hv.z * dw, hv.w * dw);
    int beg = off[v], end = off[v + 1];
    for (int i = beg; i < end; ++i) {
        int s = csr_src[i];
        float w = dinv[s] * di;
        float4 hs = reinterpret_cast<const float4*>(h1 + (size_t)s * HID)[part];
        acc.x = fmaf(hs.x, w, acc.x);
        acc.y = fmaf(hs.y, w, acc.y);
        acc.z = fmaf(hs.z, w, acc.z);
        acc.w = fmaf(hs.w, w, acc.w);
    }
    float tt[4];
    tt[0] = fmaxf(acc.x + b1[part * 4 + 0], 0.0f);
    tt[1] = fmaxf(acc.y + b1[part * 4 + 1], 0.0f);
    tt[2] = fmaxf(acc.z + b1[part * 4 + 2], 0.0f);
    tt[3] = fmaxf(acc.w + b1[part * 4 + 3], 0.0f);
    float o[NC];
#pragma unroll
    for (int c = 0; c < NC; ++c) o[c] = 0.0f;
#pragma unroll
    for (int j = 0; j < 4; ++j) {
        int k = part * 4 + j;
#pragma unroll
        for (int c = 0; c < NC; ++c) o[c] = fmaf(tt[j], W2[k * NC + c], o[c]);
    }
#pragma unroll
    for (int c = 0; c < NC; ++c) {
        o[c] += __shfl_xor(o[c], 1);
        o[c] += __shfl_xor(o[c], 2);
    }
    float4* hp = reinterpret_cast<float4*>(h2 + (size_t)v * 8);
    if (part == 0) hp[0] = make_float4(o[0], o[1], o[2], o[3]);
    if (part == 1) hp[1] = make_float4(o[4], o[5], o[6], 0.0f);
}

// ------------------- gather layer 2 + bias + log_softmax (fused, 1 th/v) ----
__global__ void k_gather2(const float* __restrict__ h2, const int* __restrict__ csr_src,
                          const int* __restrict__ off, const float* __restrict__ dinv,
                          const float* __restrict__ b2, float* __restrict__ out, int n) {
    int v = blockIdx.x * blockDim.x + threadIdx.x;
    if (v >= n) return;
    float di = dinv[v];
    float dw = di * di;
    const float4* hr = reinterpret_cast<const float4*>(h2 + (size_t)v * 8);
    float4 s0 = hr[0], s1 = hr[1];
    float4 a0 = make_float4(s0.x * dw, s0.y * dw, s0.z * dw, s0.w * dw);
    float4 a1 = make_float4(s1.x * dw, s1.y * dw, s1.z * dw, 0.0f);
    int beg = off[v], end = off[v + 1];
    for (int i = beg; i < end; ++i) {
        int s = csr_src[i];
        float w = dinv[s] * di;
        const float4* hs = reinterpret_cast<const float4*>(h2 + (size_t)s * 8);
        float4 v0 = hs[0], v1 = hs[1];
        a0.x = fmaf(v0.x, w, a0.x);
        a0.y = fmaf(v0.y, w, a0.y);
        a0.z = fmaf(v0.z, w, a0.z);
        a0.w = fmaf(v0.w, w, a0.w);
        a1.x = fmaf(v1.x, w, a1.x);
        a1.y = fmaf(v1.y, w, a1.y);
        a1.z = fmaf(v1.z, w, a1.z);
    }
    float z[NC];
    z[0] = a0.x + b2[0]; z[1] = a0.y + b2[1]; z[2] = a0.z + b2[2]; z[3] = a0.w + b2[3];
    z[4] = a1.x + b2[4]; z[5] = a1.y + b2[5]; z[6] = a1.z + b2[6];
    float m = z[0];
#pragma unroll
    for (int c = 1; c < NC; ++c) m = fmaxf(m, z[c]);
    float sum = 0.0f;
#pragma unroll
    for (int c = 0; c < NC; ++c) sum += expf(z[c] - m);
    float lse = logf(sum) + m;
#pragma unroll
    for (int c = 0; c < NC; ++c) out[(size_t)v * NC + c] = z[c] - lse;
}

// -----------------------------------------------------------------------------
extern "C" void kernel_launch(void* const* d_in, const int* in_sizes, int n_in,
                              void* d_out, int out_size, void* d_ws, size_t ws_size,
                              hipStream_t stream) {
    const float* x  = (const float*)d_in[0];
    const int*   ei = (const int*)d_in[1];
    const float* W1 = (const float*)d_in[2];
    const float* b1 = (const float*)d_in[3];
    const float* W2 = (const float*)d_in[4];
    const float* b2 = (const float*)d_in[5];

    int n = in_sizes[0] / IN_FEAT;
    int E = in_sizes[1] / 2;
    const int* src = ei;
    const int* dst = ei + E;
    const iv4* dst4 = (const iv4*)dst;
    int NB = (n + NPB - 1) >> NPB_SH;

    // workspace layout (16B-aligned chunks first)
    char* p = (char*)d_ws;
    float* h1      = (float*)p;   p += (size_t)HID * n * sizeof(float);   // 6.4 MB
    float* h2      = (float*)p;   p += (size_t)8 * n * sizeof(float);     // 3.2 MB
    int*   csr_src = (int*)p;     p += (size_t)E * sizeof(int);           // 12.8 MB (binned + sorted)
    unsigned char* bdl = (unsigned char*)p; p += ((size_t)E + 15) & ~15;  // 3.2 MB
    int*   deg     = (int*)p;     p += (size_t)n * sizeof(int);
    int*   gcur    = (int*)p;     p += (size_t)NBMAX * sizeof(int);
    int*   off     = (int*)p;     p += (size_t)(n + 1) * sizeof(int);
    float* dinv    = (float*)p;   p += (size_t)n * sizeof(float);
    int*   btot    = (int*)p;     p += (size_t)128 * sizeof(int);
    int*   bcar    = (int*)p;     p += (size_t)128 * sizeof(int);

    const int tb = 256;
    int E4 = E >> 2;
    int gE4 = (E4 + tb - 1) / tb;
    int gN = (n + tb - 1) / tb;
    int gN4 = (4 * n + tb - 1) / tb;
    int nb = (n + 1023) / 1024;
    int nchunk = (E + P1_EDGES - 1) / P1_EDGES;

    hipMemsetAsync(deg, 0, ((size_t)n + NBMAX) * sizeof(int), stream);  // deg + gcur
    k_count  <<<gE4, tb, 0, stream>>>(dst4, dst, deg, E);
    k_scanA  <<<nb, 1024, 0, stream>>>(deg, off, dinv, btot, n);
    k_scanB  <<<1, 128, 0, stream>>>(btot, bcar, nb);
    k_scanC  <<<nb, 1024, 0, stream>>>(off, bcar, n, E);
    k_bin    <<<nchunk, tb, 0, stream>>>(src, dst, off, gcur, csr_src, bdl, E, NB);
    k_sort   <<<NB, tb, 0, stream>>>(csr_src, bdl, off, src, dst, n, E);
    k_gemm1  <<<gN,  tb, 0, stream>>>(x, W1, h1, n);
    k_gather1<<<gN4, tb, 0, stream>>>(h1, csr_src, off, dinv, b1, W2, h2, n);
    k_gather2<<<gN,  tb, 0, stream>>>(h2, csr_src, off, dinv, b2, (float*)d_out, n);
}

// Round 10
// 269.715 us; speedup vs baseline: 1.9124x; 1.6652x over previous
//
#include <hip/hip_runtime.h>

#define IN_FEAT 512
#define HID 16
#define NC 7

#define NPB    128         // nodes per bucket
#define NPB_SH 7
#define NBMAX  1024        // max buckets (n <= 131072; packing needs n < 2^20)
#define CAPB   5120        // per-bucket binned capacity (mean 4090, +16 sigma)
#define CAPS   8192        // sort-stage LDS capacity (32 KB)
#define P1_EDGES 8192      // edges per bin block
#define P1_EPT   32        // edges per thread (256 thr)

// ---------------- pass 1: bin edges into fixed-capacity bucket regions ------
// No prior scan needed. Per block: LDS bucket histogram, ONE returning global
// atomic per (block,bucket) reserves a contiguous run, then packed entries
// (src | dl<<20) land in block-exclusive slots. Global atomics: ~306K total
// (vs 3.2M per-node in the old k_count -> 100MB of memory-side atomic WRITE).
__global__ __launch_bounds__(256) void k_bin2(const int* __restrict__ src,
                                              const int* __restrict__ dst,
                                              int* __restrict__ gcur,
                                              int* __restrict__ binned,
                                              int E, int NB) {
    __shared__ int cnt[NBMAX];
    __shared__ int sbase[NBMAX];
    __shared__ int lcur[NBMAX];
    int tid = threadIdx.x;
    for (int b = tid; b < NB; b += 256) { cnt[b] = 0; lcur[b] = 0; }
    __syncthreads();

    int base = blockIdx.x * P1_EDGES + tid;
    int d[P1_EPT];
#pragma unroll
    for (int i = 0; i < P1_EPT; ++i) {
        int e = base + i * 256;
        d[i] = (e < E) ? __builtin_nontemporal_load(dst + e) : -1;
    }
#pragma unroll
    for (int i = 0; i < P1_EPT; ++i) {
        if (d[i] >= 0) atomicAdd(&cnt[d[i] >> NPB_SH], 1);
    }
    __syncthreads();
    for (int b = tid; b < NB; b += 256) {
        int c = cnt[b];
        sbase[b] = c ? atomicAdd(&gcur[b], c) : 0;   // counts past CAPB too (true size)
    }
    __syncthreads();
#pragma unroll
    for (int i = 0; i < P1_EPT; ++i) {
        if (d[i] < 0) continue;
        int e = base + i * 256;
        int s = __builtin_nontemporal_load(src + e);
        int b = d[i] >> NPB_SH;
        int pos = sbase[b] + atomicAdd(&lcur[b], 1);
        if (pos < CAPB)
            binned[(size_t)b * CAPB + pos] = s | ((d[i] & (NPB - 1)) << 20);
    }
}

// ---------------- tiny scan over bucket totals (<=1024, one block) ----------
__global__ __launch_bounds__(1024) void k_bscan(const int* __restrict__ gcur,
                                                int* __restrict__ boff,
                                                int* __restrict__ off,
                                                int NB, int n, int E) {
    __shared__ int wsum[16];
    int tid = threadIdx.x, lane = tid & 63, wid = tid >> 6;
    int v = (tid < NB) ? gcur[tid] : 0;
    int incl = v;
#pragma unroll
    for (int o = 1; o < 64; o <<= 1) {
        int t = __shfl_up(incl, o, 64);
        if (lane >= o) incl += t;
    }
    if (lane == 63) wsum[wid] = incl;
    __syncthreads();
    int wpre = 0;
    for (int k = 0; k < wid; ++k) wpre += wsum[k];
    int ex = wpre + incl - v;
    if (tid < NB) boff[tid] = ex;
    if (tid == 0) off[n] = E;
}

// -------- pass 2: per-bucket sort + degree/off/dinv derivation (fused) ------
// One block per bucket. 128-counter LDS histogram over the bucket's entries
// gives per-node degree (-> dinv) and, with the bucket base, per-node CSR
// offsets. Entries are then placed via LDS cursors into an LDS stage and
// written out fully coalesced. Overflowed buckets (impossible for uniform
// dst, guaranteed-correct anyway) fall back to scanning the raw edge list.
__global__ __launch_bounds__(256) void k_sort2(const int* __restrict__ binned,
                                               const int* __restrict__ gcur,
                                               const int* __restrict__ boff,
                                               int* __restrict__ off,
                                               float* __restrict__ dinv,
                                               int* __restrict__ csr,
                                               const int* __restrict__ src,
                                               const int* __restrict__ dst,
                                               int n, int E) {
    __shared__ int hist[NPB];
    __shared__ int hoff[NPB];
    __shared__ int cur[NPB];
    __shared__ int wtot[2];
    __shared__ int stage[CAPS];
    int b = blockIdx.x;
    int lo = b << NPB_SH;
    int nn = min(NPB, n - lo);
    int tid = threadIdx.x;
    int tot = gcur[b];
    int base = boff[b];
    bool fits = (tot <= CAPB) && (tot <= CAPS);
    if (tid < NPB) { hist[tid] = 0; cur[tid] = 0; }
    __syncthreads();

    const int* bb = binned + (size_t)b * CAPB;
    if (fits) {
        for (int k = tid; k < tot; k += 256)
            atomicAdd(&hist[(bb[k] >> 20) & (NPB - 1)], 1);
    } else {
        for (int e = tid; e < E; e += 256) {
            int dd = dst[e];
            if ((dd >> NPB_SH) == b) atomicAdd(&hist[dd & (NPB - 1)], 1);
        }
    }
    __syncthreads();

    // exclusive scan of 128 counters (2 waves) + off/dinv epilogue
    int v = 0, incl = 0;
    if (tid < NPB) {
        v = hist[tid];
        incl = v;
#pragma unroll
        for (int o = 1; o < 64; o <<= 1) {
            int t = __shfl_up(incl, o, 64);
            if ((tid & 63) >= o) incl += t;
        }
        if ((tid & 63) == 63) wtot[tid >> 6] = incl;
    }
    __syncthreads();
    if (tid < NPB) {
        int ex = incl - v + ((tid >= 64) ? wtot[0] : 0);
        hoff[tid] = ex;
        if (tid < nn) {
            off[lo + tid] = base + ex;
            dinv[lo + tid] = rsqrtf((float)v + 1.0f);  // +1 = self-loop
        }
    }
    __syncthreads();

    if (fits) {
        for (int k = tid; k < tot; k += 256) {
            int e = bb[k];
            int dl = (e >> 20) & (NPB - 1);
            int p = hoff[dl] + atomicAdd(&cur[dl], 1);
            stage[p] = e & 0xFFFFF;
        }
        __syncthreads();
        for (int k = tid; k < tot; k += 256) csr[base + k] = stage[k];
    } else {
        for (int e = tid; e < E; e += 256) {
            int dd = dst[e];
            if ((dd >> NPB_SH) == b) {
                int dl = dd & (NPB - 1);
                int p = base + hoff[dl] + atomicAdd(&cur[dl], 1);
                csr[p] = src[e];
            }
        }
    }
}

// ------------------------------------------------------- layer 1: x @ W1 ----
// One thread per row; W indices wave-uniform -> scalar-pipe s_loads.
__global__ void k_gemm1(const float* __restrict__ x, const float* __restrict__ W,
                        float* __restrict__ h1, int n) {
    int row = blockIdx.x * blockDim.x + threadIdx.x;
    if (row >= n) return;
    const float4* xr = reinterpret_cast<const float4*>(x + (size_t)row * IN_FEAT);
    float acc[HID];
#pragma unroll
    for (int c = 0; c < HID; ++c) acc[c] = 0.0f;
#pragma unroll 2
    for (int kt = 0; kt < IN_FEAT / 4; ++kt) {
        float4 xv = xr[kt];
        const float* wk = W + (size_t)kt * 4 * HID;
#pragma unroll
        for (int c = 0; c < HID; ++c) acc[c] = fmaf(xv.x, wk[c], acc[c]);
#pragma unroll
        for (int c = 0; c < HID; ++c) acc[c] = fmaf(xv.y, wk[HID + c], acc[c]);
#pragma unroll
        for (int c = 0; c < HID; ++c) acc[c] = fmaf(xv.z, wk[2 * HID + c], acc[c]);
#pragma unroll
        for (int c = 0; c < HID; ++c) acc[c] = fmaf(xv.w, wk[3 * HID + c], acc[c]);
    }
    float4* hp = reinterpret_cast<float4*>(h1 + (size_t)row * HID);
#pragma unroll
    for (int j = 0; j < 4; ++j)
        hp[j] = make_float4(acc[4 * j], acc[4 * j + 1], acc[4 * j + 2], acc[4 * j + 3]);
}

// ------------------- gather layer 1 + bias + relu + @W2 (fused, 4 lanes/v) --
__global__ void k_gather1(const float* __restrict__ h1, const int* __restrict__ csr_src,
                          const int* __restrict__ off, const float* __restrict__ dinv,
                          const float* __restrict__ b1, const float* __restrict__ W2,
                          float* __restrict__ h2, int n) {
    int t = blockIdx.x * blockDim.x + threadIdx.x;
    int v = t >> 2, part = t & 3;
    if (v >= n) return;
    float di = dinv[v];
    float4 hv = reinterpret_cast<const float4*>(h1 + (size_t)v * HID)[part];
    float dw = di * di;
    float4 acc = make_float4(hv.x * dw, hv.y * dw, hv.z * dw, hv.w * dw);
    int beg = off[v], end = off[v + 1];
    for (int i = beg; i < end; ++i) {
        int s = csr_src[i];
        float w = dinv[s] * di;
        float4 hs = reinterpret_cast<const float4*>(h1 + (size_t)s * HID)[part];
        acc.x = fmaf(hs.x, w, acc.x);
        acc.y = fmaf(hs.y, w, acc.y);
        acc.z = fmaf(hs.z, w, acc.z);
        acc.w = fmaf(hs.w, w, acc.w);
    }
    float tt[4];
    tt[0] = fmaxf(acc.x + b1[part * 4 + 0], 0.0f);
    tt[1] = fmaxf(acc.y + b1[part * 4 + 1], 0.0f);
    tt[2] = fmaxf(acc.z + b1[part * 4 + 2], 0.0f);
    tt[3] = fmaxf(acc.w + b1[part * 4 + 3], 0.0f);
    float o[NC];
#pragma unroll
    for (int c = 0; c < NC; ++c) o[c] = 0.0f;
#pragma unroll
    for (int j = 0; j < 4; ++j) {
        int k = part * 4 + j;
#pragma unroll
        for (int c = 0; c < NC; ++c) o[c] = fmaf(tt[j], W2[k * NC + c], o[c]);
    }
#pragma unroll
    for (int c = 0; c < NC; ++c) {
        o[c] += __shfl_xor(o[c], 1);
        o[c] += __shfl_xor(o[c], 2);
    }
    float4* hp = reinterpret_cast<float4*>(h2 + (size_t)v * 8);
    if (part == 0) hp[0] = make_float4(o[0], o[1], o[2], o[3]);
    if (part == 1) hp[1] = make_float4(o[4], o[5], o[6], 0.0f);
}

// ------------------- gather layer 2 + bias + log_softmax (fused, 1 th/v) ----
__global__ void k_gather2(const float* __restrict__ h2, const int* __restrict__ csr_src,
                          const int* __restrict__ off, const float* __restrict__ dinv,
                          const float* __restrict__ b2, float* __restrict__ out, int n) {
    int v = blockIdx.x * blockDim.x + threadIdx.x;
    if (v >= n) return;
    float di = dinv[v];
    float dw = di * di;
    const float4* hr = reinterpret_cast<const float4*>(h2 + (size_t)v * 8);
    float4 s0 = hr[0], s1 = hr[1];
    float4 a0 = make_float4(s0.x * dw, s0.y * dw, s0.z * dw, s0.w * dw);
    float4 a1 = make_float4(s1.x * dw, s1.y * dw, s1.z * dw, 0.0f);
    int beg = off[v], end = off[v + 1];
    for (int i = beg; i < end; ++i) {
        int s = csr_src[i];
        float w = dinv[s] * di;
        const float4* hs = reinterpret_cast<const float4*>(h2 + (size_t)s * 8);
        float4 v0 = hs[0], v1 = hs[1];
        a0.x = fmaf(v0.x, w, a0.x);
        a0.y = fmaf(v0.y, w, a0.y);
        a0.z = fmaf(v0.z, w, a0.z);
        a0.w = fmaf(v0.w, w, a0.w);
        a1.x = fmaf(v1.x, w, a1.x);
        a1.y = fmaf(v1.y, w, a1.y);
        a1.z = fmaf(v1.z, w, a1.z);
    }
    float z[NC];
    z[0] = a0.x + b2[0]; z[1] = a0.y + b2[1]; z[2] = a0.z + b2[2]; z[3] = a0.w + b2[3];
    z[4] = a1.x + b2[4]; z[5] = a1.y + b2[5]; z[6] = a1.z + b2[6];
    float m = z[0];
#pragma unroll
    for (int c = 1; c < NC; ++c) m = fmaxf(m, z[c]);
    float sum = 0.0f;
#pragma unroll
    for (int c = 0; c < NC; ++c) sum += expf(z[c] - m);
    float lse = logf(sum) + m;
#pragma unroll
    for (int c = 0; c < NC; ++c) out[(size_t)v * NC + c] = z[c] - lse;
}

// -----------------------------------------------------------------------------
extern "C" void kernel_launch(void* const* d_in, const int* in_sizes, int n_in,
                              void* d_out, int out_size, void* d_ws, size_t ws_size,
                              hipStream_t stream) {
    const float* x  = (const float*)d_in[0];
    const int*   ei = (const int*)d_in[1];
    const float* W1 = (const float*)d_in[2];
    const float* b1 = (const float*)d_in[3];
    const float* W2 = (const float*)d_in[4];
    const float* b2 = (const float*)d_in[5];

    int n = in_sizes[0] / IN_FEAT;
    int E = in_sizes[1] / 2;
    const int* src = ei;
    const int* dst = ei + E;
    int NB = (n + NPB - 1) >> NPB_SH;

    // ws layout. binned is dead after k_sort2; h1/h2 alias it (gemm1 runs later).
    char* p = (char*)d_ws;
    int*   binned  = (int*)p;
    float* h1      = (float*)p;   p += (size_t)NB * CAPB * sizeof(int);  // 16.0 MB
    float* h2      = h1 + (size_t)HID * n;                               // inside alias
    int*   csr_src = (int*)p;     p += (size_t)E * sizeof(int);          // 12.8 MB
    int*   gcur    = (int*)p;     p += (size_t)NBMAX * sizeof(int);
    int*   boff    = (int*)p;     p += (size_t)NBMAX * sizeof(int);
    int*   off     = (int*)p;     p += (size_t)(n + 1) * sizeof(int);
    float* dinv    = (float*)p;   p += (size_t)n * sizeof(float);

    const int tb = 256;
    int gN = (n + tb - 1) / tb;
    int gN4 = (4 * n + tb - 1) / tb;
    int nchunk = (E + P1_EDGES - 1) / P1_EDGES;

    hipMemsetAsync(gcur, 0, (size_t)NBMAX * sizeof(int), stream);
    k_bin2   <<<nchunk, tb, 0, stream>>>(src, dst, gcur, binned, E, NB);
    k_bscan  <<<1, 1024, 0, stream>>>(gcur, boff, off, NB, n, E);
    k_sort2  <<<NB, tb, 0, stream>>>(binned, gcur, boff, off, dinv, csr_src,
                                     src, dst, n, E);
    k_gemm1  <<<gN,  tb, 0, stream>>>(x, W1, h1, n);
    k_gather1<<<gN4, tb, 0, stream>>>(h1, csr_src, off, dinv, b1, W2, h2, n);
    k_gather2<<<gN,  tb, 0, stream>>>(h2, csr_src, off, dinv, b2, (float*)d_out, n);
}

// Round 11
// 266.864 us; speedup vs baseline: 1.9328x; 1.0107x over previous
//
#include <hip/hip_runtime.h>

#define IN_FEAT 512
#define HID 16
#define NC 7

#define NPB    128         // nodes per bucket
#define NPB_SH 7
#define NBMAX  1024        // max buckets (n <= 131072; packing needs n < 2^20)
#define CAPB   5120        // per-bucket binned capacity (mean 4090, +16 sigma)
#define CAPS   8192        // sort-stage LDS capacity (32 KB)
#define P1_EDGES 8192      // edges per bin block
#define P1_EPT   32        // edges per thread (256 thr)

typedef float fv4 __attribute__((ext_vector_type(4)));

// ---------------- pass 1: bin edges into fixed-capacity bucket regions ------
// One-pass ticketing: per-edge LDS ticket in the same pass as the dst read
// (was: separate count pass -> 2x LDS atomics). ONE returning global atomic
// per (block,bucket) reserves the contiguous run; packed entries
// (src | dl<<20) land in block-exclusive slots.
__global__ __launch_bounds__(256) void k_bin2(const int* __restrict__ src,
                                              const int* __restrict__ dst,
                                              int* __restrict__ gcur,
                                              int* __restrict__ binned,
                                              int E, int NB) {
    __shared__ int lcur[NBMAX];
    __shared__ int sbase[NBMAX];
    int tid = threadIdx.x;
    for (int b = tid; b < NB; b += 256) lcur[b] = 0;
    __syncthreads();

    int base = blockIdx.x * P1_EDGES + tid;
    int d[P1_EPT];
    int lp[P1_EPT];
#pragma unroll
    for (int i = 0; i < P1_EPT; ++i) {
        int e = base + i * 256;
        d[i] = (e < E) ? __builtin_nontemporal_load(dst + e) : -1;
    }
#pragma unroll
    for (int i = 0; i < P1_EPT; ++i) {
        if (d[i] >= 0) lp[i] = atomicAdd(&lcur[d[i] >> NPB_SH], 1);
    }
    __syncthreads();
    for (int b = tid; b < NB; b += 256) {
        int c = lcur[b];
        sbase[b] = c ? atomicAdd(&gcur[b], c) : 0;   // true totals (past CAPB too)
    }
    __syncthreads();
#pragma unroll
    for (int i = 0; i < P1_EPT; ++i) {
        if (d[i] < 0) continue;
        int e = base + i * 256;
        int s = __builtin_nontemporal_load(src + e);
        int b = d[i] >> NPB_SH;
        int pos = sbase[b] + lp[i];
        if (pos < CAPB)
            binned[(size_t)b * CAPB + pos] = s | ((d[i] & (NPB - 1)) << 20);
    }
}

// ---------------- tiny scan over bucket totals (<=1024, one block) ----------
__global__ __launch_bounds__(1024) void k_bscan(const int* __restrict__ gcur,
                                                int* __restrict__ boff,
                                                int* __restrict__ off,
                                                int NB, int n, int E) {
    __shared__ int wsum[16];
    int tid = threadIdx.x, lane = tid & 63, wid = tid >> 6;
    int v = (tid < NB) ? gcur[tid] : 0;
    int incl = v;
#pragma unroll
    for (int o = 1; o < 64; o <<= 1) {
        int t = __shfl_up(incl, o, 64);
        if (lane >= o) incl += t;
    }
    if (lane == 63) wsum[wid] = incl;
    __syncthreads();
    int wpre = 0;
    for (int k = 0; k < wid; ++k) wpre += wsum[k];
    int ex = wpre + incl - v;
    if (tid < NB) boff[tid] = ex;
    if (tid == 0) off[n] = E;
}

// -------- pass 2: per-bucket sort + degree/off/dinv derivation (fused) ------
__global__ __launch_bounds__(256) void k_sort2(const int* __restrict__ binned,
                                               const int* __restrict__ gcur,
                                               const int* __restrict__ boff,
                                               int* __restrict__ off,
                                               float* __restrict__ dinv,
                                               int* __restrict__ csr,
                                               const int* __restrict__ src,
                                               const int* __restrict__ dst,
                                               int n, int E) {
    __shared__ int hist[NPB];
    __shared__ int hoff[NPB];
    __shared__ int cur[NPB];
    __shared__ int wtot[2];
    __shared__ int stage[CAPS];
    int b = blockIdx.x;
    int lo = b << NPB_SH;
    int nn = min(NPB, n - lo);
    int tid = threadIdx.x;
    int tot = gcur[b];
    int base = boff[b];
    bool fits = (tot <= CAPB) && (tot <= CAPS);
    if (tid < NPB) { hist[tid] = 0; cur[tid] = 0; }
    __syncthreads();

    const int* bb = binned + (size_t)b * CAPB;
    if (fits) {
        for (int k = tid; k < tot; k += 256)
            atomicAdd(&hist[(bb[k] >> 20) & (NPB - 1)], 1);
    } else {
        for (int e = tid; e < E; e += 256) {
            int dd = dst[e];
            if ((dd >> NPB_SH) == b) atomicAdd(&hist[dd & (NPB - 1)], 1);
        }
    }
    __syncthreads();

    // exclusive scan of 128 counters (2 waves) + off/dinv epilogue
    int v = 0, incl = 0;
    if (tid < NPB) {
        v = hist[tid];
        incl = v;
#pragma unroll
        for (int o = 1; o < 64; o <<= 1) {
            int t = __shfl_up(incl, o, 64);
            if ((tid & 63) >= o) incl += t;
        }
        if ((tid & 63) == 63) wtot[tid >> 6] = incl;
    }
    __syncthreads();
    if (tid < NPB) {
        int ex = incl - v + ((tid >= 64) ? wtot[0] : 0);
        hoff[tid] = ex;
        if (tid < nn) {
            off[lo + tid] = base + ex;
            dinv[lo + tid] = rsqrtf((float)v + 1.0f);  // +1 = self-loop
        }
    }
    __syncthreads();

    if (fits) {
        for (int k = tid; k < tot; k += 256) {
            int e = bb[k];
            int dl = (e >> 20) & (NPB - 1);
            int p = hoff[dl] + atomicAdd(&cur[dl], 1);
            stage[p] = e & 0xFFFFF;
        }
        __syncthreads();
        for (int k = tid; k < tot; k += 256) csr[base + k] = stage[k];
    } else {
        for (int e = tid; e < E; e += 256) {
            int dd = dst[e];
            if ((dd >> NPB_SH) == b) {
                int dl = dd & (NPB - 1);
                int p = base + hoff[dl] + atomicAdd(&cur[dl], 1);
                csr[p] = src[e];
            }
        }
    }
}

// ------------------------------------------------------- layer 1: x @ W1 ----
// One thread per row, W wave-uniform (scalar pipe). K-loop hand-batched:
// 8 independent float4 loads in flight per thread (was ~2 -> latency-bound
// at only ~6 waves/CU of TLP).
__global__ void k_gemm1(const float* __restrict__ x, const float* __restrict__ W,
                        float* __restrict__ h1, int n) {
    int row = blockIdx.x * blockDim.x + threadIdx.x;
    if (row >= n) return;
    const float4* xr = reinterpret_cast<const float4*>(x + (size_t)row * IN_FEAT);
    float acc[HID];
#pragma unroll
    for (int c = 0; c < HID; ++c) acc[c] = 0.0f;
    for (int kt0 = 0; kt0 < IN_FEAT / 4; kt0 += 8) {
        float4 xv[8];
#pragma unroll
        for (int j = 0; j < 8; ++j) xv[j] = xr[kt0 + j];   // 8 loads issue together
#pragma unroll
        for (int j = 0; j < 8; ++j) {
            const float* wk = W + (size_t)(kt0 + j) * 4 * HID;
#pragma unroll
            for (int c = 0; c < HID; ++c) acc[c] = fmaf(xv[j].x, wk[c], acc[c]);
#pragma unroll
            for (int c = 0; c < HID; ++c) acc[c] = fmaf(xv[j].y, wk[HID + c], acc[c]);
#pragma unroll
            for (int c = 0; c < HID; ++c) acc[c] = fmaf(xv[j].z, wk[2 * HID + c], acc[c]);
#pragma unroll
            for (int c = 0; c < HID; ++c) acc[c] = fmaf(xv[j].w, wk[3 * HID + c], acc[c]);
        }
    }
    float4* hp = reinterpret_cast<float4*>(h1 + (size_t)row * HID);
#pragma unroll
    for (int j = 0; j < 4; ++j)
        hp[j] = make_float4(acc[4 * j], acc[4 * j + 1], acc[4 * j + 2], acc[4 * j + 3]);
}

// ------------------- gather layer 1 + bias + relu + @W2 (fused, 4 lanes/v) --
__global__ void k_gather1(const float* __restrict__ h1, const int* __restrict__ csr_src,
                          const int* __restrict__ off, const float* __restrict__ dinv,
                          const float* __restrict__ b1, const float* __restrict__ W2,
                          float* __restrict__ h2, int n) {
    int t = blockIdx.x * blockDim.x + threadIdx.x;
    int v = t >> 2, part = t & 3;
    if (v >= n) return;
    float di = dinv[v];
    float4 hv = reinterpret_cast<const float4*>(h1 + (size_t)v * HID)[part];
    float dw = di * di;
    float4 acc = make_float4(hv.x * dw, hv.y * dw, hv.z * dw, hv.w * dw);
    int beg = off[v], end = off[v + 1];
    for (int i = beg; i < end; ++i) {
        int s = csr_src[i];
        float w = dinv[s] * di;
        float4 hs = reinterpret_cast<const float4*>(h1 + (size_t)s * HID)[part];
        acc.x = fmaf(hs.x, w, acc.x);
        acc.y = fmaf(hs.y, w, acc.y);
        acc.z = fmaf(hs.z, w, acc.z);
        acc.w = fmaf(hs.w, w, acc.w);
    }
    float tt[4];
    tt[0] = fmaxf(acc.x + b1[part * 4 + 0], 0.0f);
    tt[1] = fmaxf(acc.y + b1[part * 4 + 1], 0.0f);
    tt[2] = fmaxf(acc.z + b1[part * 4 + 2], 0.0f);
    tt[3] = fmaxf(acc.w + b1[part * 4 + 3], 0.0f);
    float o[NC];
#pragma unroll
    for (int c = 0; c < NC; ++c) o[c] = 0.0f;
#pragma unroll
    for (int j = 0; j < 4; ++j) {
        int k = part * 4 + j;
#pragma unroll
        for (int c = 0; c < NC; ++c) o[c] = fmaf(tt[j], W2[k * NC + c], o[c]);
    }
#pragma unroll
    for (int c = 0; c < NC; ++c) {
        o[c] += __shfl_xor(o[c], 1);
        o[c] += __shfl_xor(o[c], 2);
    }
    float4* hp = reinterpret_cast<float4*>(h2 + (size_t)v * 8);
    if (part == 0) hp[0] = make_float4(o[0], o[1], o[2], o[3]);
    if (part == 1) hp[1] = make_float4(o[4], o[5], o[6], 0.0f);
}

// ------------------- gather layer 2 + bias + log_softmax (fused, 1 th/v) ----
__global__ void k_gather2(const float* __restrict__ h2, const int* __restrict__ csr_src,
                          const int* __restrict__ off, const float* __restrict__ dinv,
                          const float* __restrict__ b2, float* __restrict__ out, int n) {
    int v = blockIdx.x * blockDim.x + threadIdx.x;
    if (v >= n) return;
    float di = dinv[v];
    float dw = di * di;
    const float4* hr = reinterpret_cast<const float4*>(h2 + (size_t)v * 8);
    float4 s0 = hr[0], s1 = hr[1];
    float4 a0 = make_float4(s0.x * dw, s0.y * dw, s0.z * dw, s0.w * dw);
    float4 a1 = make_float4(s1.x * dw, s1.y * dw, s1.z * dw, 0.0f);
    int beg = off[v], end = off[v + 1];
    for (int i = beg; i < end; ++i) {
        int s = csr_src[i];
        float w = dinv[s] * di;
        const float4* hs = reinterpret_cast<const float4*>(h2 + (size_t)s * 8);
        float4 v0 = hs[0], v1 = hs[1];
        a0.x = fmaf(v0.x, w, a0.x);
        a0.y = fmaf(v0.y, w, a0.y);
        a0.z = fmaf(v0.z, w, a0.z);
        a0.w = fmaf(v0.w, w, a0.w);
        a1.x = fmaf(v1.x, w, a1.x);
        a1.y = fmaf(v1.y, w, a1.y);
        a1.z = fmaf(v1.z, w, a1.z);
    }
    float z[NC];
    z[0] = a0.x + b2[0]; z[1] = a0.y + b2[1]; z[2] = a0.z + b2[2]; z[3] = a0.w + b2[3];
    z[4] = a1.x + b2[4]; z[5] = a1.y + b2[5]; z[6] = a1.z + b2[6];
    float m = z[0];
#pragma unroll
    for (int c = 1; c < NC; ++c) m = fmaxf(m, z[c]);
    float sum = 0.0f;
#pragma unroll
    for (int c = 0; c < NC; ++c) sum += expf(z[c] - m);
    float lse = logf(sum) + m;
#pragma unroll
    for (int c = 0; c < NC; ++c) out[(size_t)v * NC + c] = z[c] - lse;
}

// -----------------------------------------------------------------------------
extern "C" void kernel_launch(void* const* d_in, const int* in_sizes, int n_in,
                              void* d_out, int out_size, void* d_ws, size_t ws_size,
                              hipStream_t stream) {
    const float* x  = (const float*)d_in[0];
    const int*   ei = (const int*)d_in[1];
    const float* W1 = (const float*)d_in[2];
    const float* b1 = (const float*)d_in[3];
    const float* W2 = (const float*)d_in[4];
    const float* b2 = (const float*)d_in[5];

    int n = in_sizes[0] / IN_FEAT;
    int E = in_sizes[1] / 2;
    const int* src = ei;
    const int* dst = ei + E;
    int NB = (n + NPB - 1) >> NPB_SH;

    // ws layout. binned is dead after k_sort2; h1/h2 alias it (gemm1 runs later).
    char* p = (char*)d_ws;
    int*   binned  = (int*)p;
    float* h1      = (float*)p;   p += (size_t)NB * CAPB * sizeof(int);  // 16.0 MB
    float* h2      = h1 + (size_t)HID * n;                               // inside alias
    int*   csr_src = (int*)p;     p += (size_t)E * sizeof(int);          // 12.8 MB
    int*   gcur    = (int*)p;     p += (size_t)NBMAX * sizeof(int);
    int*   boff    = (int*)p;     p += (size_t)NBMAX * sizeof(int);
    int*   off     = (int*)p;     p += (size_t)(n + 1) * sizeof(int);
    float* dinv    = (float*)p;   p += (size_t)n * sizeof(float);

    const int tb = 256;
    int gN = (n + tb - 1) / tb;
    int gN4 = (4 * n + tb - 1) / tb;
    int nchunk = (E + P1_EDGES - 1) / P1_EDGES;

    hipMemsetAsync(gcur, 0, (size_t)NBMAX * sizeof(int), stream);
    k_bin2   <<<nchunk, tb, 0, stream>>>(src, dst, gcur, binned, E, NB);
    k_bscan  <<<1, 1024, 0, stream>>>(gcur, boff, off, NB, n, E);
    k_sort2  <<<NB, tb, 0, stream>>>(binned, gcur, boff, off, dinv, csr_src,
                                     src, dst, n, E);
    k_gemm1  <<<gN,  tb, 0, stream>>>(x, W1, h1, n);
    k_gather1<<<gN4, tb, 0, stream>>>(h1, csr_src, off, dinv, b1, W2, h2, n);
    k_gather2<<<gN,  tb, 0, stream>>>(h2, csr_src, off, dinv, b2, (float*)d_out, n);
}

// Round 12
// 253.519 us; speedup vs baseline: 2.0346x; 1.0526x over previous
//
#include <hip/hip_runtime.h>

#define IN_FEAT 512
#define HID 16
#define NC 7

#define NPB    128         // nodes per bucket
#define NPB_SH 7
#define NBMAX  1024        // max buckets (n <= 131072; packing needs n < 2^20)
#define CAPB   5120        // per-bucket binned capacity (mean 4090, +16 sigma)
#define CAPS   8192        // sort-stage LDS capacity (32 KB)
#define P1_EDGES 8192      // edges per bin block
#define P1_EPT   32        // edges per thread (256 thr)

// ------------- fused: edge binning (blocks < nchunk) + x@W1 (rest) ----------
// The two phases are independent; role-split makes them run concurrently:
// bin is LDS-atomic-bound at 9% HBM, gemm is VMEM-load-bound -> complementary
// pipes. One returning global atomic per (block,bucket) reserves a contiguous
// run; packed entries (src | dl<<20) land in block-exclusive slots.
__global__ __launch_bounds__(256) void k_binmm(const int* __restrict__ src,
                                               const int* __restrict__ dst,
                                               int* __restrict__ gcur,
                                               int* __restrict__ binned,
                                               const float* __restrict__ x,
                                               const float* __restrict__ W,
                                               float* __restrict__ h1,
                                               int E, int NB, int nchunk, int n) {
    int tid = threadIdx.x;
    if ((int)blockIdx.x < nchunk) {
        // ------------------------------ bin role ----------------------------
        __shared__ int lcur[NBMAX];
        __shared__ int sbase[NBMAX];
        for (int b = tid; b < NB; b += 256) lcur[b] = 0;
        __syncthreads();

        int base = blockIdx.x * P1_EDGES + tid;
        int d[P1_EPT];
        int lp[P1_EPT];
#pragma unroll
        for (int i = 0; i < P1_EPT; ++i) {
            int e = base + i * 256;
            d[i] = (e < E) ? __builtin_nontemporal_load(dst + e) : -1;
        }
#pragma unroll
        for (int i = 0; i < P1_EPT; ++i) {
            if (d[i] >= 0) lp[i] = atomicAdd(&lcur[d[i] >> NPB_SH], 1);
        }
        __syncthreads();
        for (int b = tid; b < NB; b += 256) {
            int c = lcur[b];
            sbase[b] = c ? atomicAdd(&gcur[b], c) : 0;  // true totals (past CAPB too)
        }
        __syncthreads();
#pragma unroll
        for (int i = 0; i < P1_EPT; ++i) {
            if (d[i] < 0) continue;
            int e = base + i * 256;
            int s = __builtin_nontemporal_load(src + e);
            int b = d[i] >> NPB_SH;
            int pos = sbase[b] + lp[i];
            if (pos < CAPB)
                binned[(size_t)b * CAPB + pos] = s | ((d[i] & (NPB - 1)) << 20);
        }
    } else {
        // ------------------------------ gemm role ---------------------------
        // One thread per row, W wave-uniform (scalar pipe), 8 loads in flight.
        int row = ((int)blockIdx.x - nchunk) * 256 + tid;
        if (row >= n) return;
        const float4* xr = reinterpret_cast<const float4*>(x + (size_t)row * IN_FEAT);
        float acc[HID];
#pragma unroll
        for (int c = 0; c < HID; ++c) acc[c] = 0.0f;
        for (int kt0 = 0; kt0 < IN_FEAT / 4; kt0 += 8) {
            float4 xv[8];
#pragma unroll
            for (int j = 0; j < 8; ++j) xv[j] = xr[kt0 + j];
#pragma unroll
            for (int j = 0; j < 8; ++j) {
                const float* wk = W + (size_t)(kt0 + j) * 4 * HID;
#pragma unroll
                for (int c = 0; c < HID; ++c) acc[c] = fmaf(xv[j].x, wk[c], acc[c]);
#pragma unroll
                for (int c = 0; c < HID; ++c) acc[c] = fmaf(xv[j].y, wk[HID + c], acc[c]);
#pragma unroll
                for (int c = 0; c < HID; ++c) acc[c] = fmaf(xv[j].z, wk[2 * HID + c], acc[c]);
#pragma unroll
                for (int c = 0; c < HID; ++c) acc[c] = fmaf(xv[j].w, wk[3 * HID + c], acc[c]);
            }
        }
        float4* hp = reinterpret_cast<float4*>(h1 + (size_t)row * HID);
#pragma unroll
        for (int j = 0; j < 4; ++j)
            hp[j] = make_float4(acc[4 * j], acc[4 * j + 1], acc[4 * j + 2], acc[4 * j + 3]);
    }
}

// -------- pass 2: per-bucket sort + deg/off/dinv + inline bucket-base scan --
// boff computed per block (reduce gcur[0..b), <=4 L2 reads/thread) -- the
// separate k_bscan kernel is gone.
__global__ __launch_bounds__(256) void k_sort2(const int* __restrict__ binned,
                                               const int* __restrict__ gcur,
                                               int* __restrict__ off,
                                               float* __restrict__ dinv,
                                               int* __restrict__ csr,
                                               const int* __restrict__ src,
                                               const int* __restrict__ dst,
                                               int n, int E, int NB) {
    __shared__ int hist[NPB];
    __shared__ int hoff[NPB];
    __shared__ int cur[NPB];
    __shared__ int wtot[4];
    __shared__ int s_base;
    __shared__ int stage[CAPS];
    int b = blockIdx.x;
    int lo = b << NPB_SH;
    int nn = min(NPB, n - lo);
    int tid = threadIdx.x;
    int lane = tid & 63, wid = tid >> 6;
    int tot = gcur[b];

    // inline exclusive prefix over bucket totals -> base
    int pre = 0;
    for (int k = tid; k < b; k += 256) pre += gcur[k];
#pragma unroll
    for (int o = 32; o >= 1; o >>= 1) pre += __shfl_xor(pre, o, 64);
    if (lane == 0) wtot[wid] = pre;
    if (tid < NPB) { hist[tid] = 0; cur[tid] = 0; }
    __syncthreads();
    if (tid == 0) s_base = wtot[0] + wtot[1] + wtot[2] + wtot[3];
    __syncthreads();
    int base = s_base;
    bool fits = (tot <= CAPB) && (tot <= CAPS);

    const int* bb = binned + (size_t)b * CAPB;
    if (fits) {
        for (int k = tid; k < tot; k += 256)
            atomicAdd(&hist[(bb[k] >> 20) & (NPB - 1)], 1);
    } else {
        for (int e = tid; e < E; e += 256) {
            int dd = dst[e];
            if ((dd >> NPB_SH) == b) atomicAdd(&hist[dd & (NPB - 1)], 1);
        }
    }
    __syncthreads();

    // exclusive scan of 128 counters (2 waves) + off/dinv epilogue
    int v = 0, incl = 0;
    if (tid < NPB) {
        v = hist[tid];
        incl = v;
#pragma unroll
        for (int o = 1; o < 64; o <<= 1) {
            int t = __shfl_up(incl, o, 64);
            if ((tid & 63) >= o) incl += t;
        }
        if ((tid & 63) == 63) wtot[tid >> 6] = incl;
    }
    __syncthreads();
    if (tid < NPB) {
        int ex = incl - v + ((tid >= 64) ? wtot[0] : 0);
        hoff[tid] = ex;
        if (tid < nn) {
            off[lo + tid] = base + ex;
            dinv[lo + tid] = rsqrtf((float)v + 1.0f);  // +1 = self-loop
        }
    }
    if (b == NB - 1 && tid == 0) off[n] = base + tot;  // == E (true totals)
    __syncthreads();

    if (fits) {
        for (int k = tid; k < tot; k += 256) {
            int e = bb[k];
            int dl = (e >> 20) & (NPB - 1);
            int p = hoff[dl] + atomicAdd(&cur[dl], 1);
            stage[p] = e & 0xFFFFF;
        }
        __syncthreads();
        for (int k = tid; k < tot; k += 256) csr[base + k] = stage[k];
    } else {
        for (int e = tid; e < E; e += 256) {
            int dd = dst[e];
            if ((dd >> NPB_SH) == b) {
                int dl = dd & (NPB - 1);
                int p = base + hoff[dl] + atomicAdd(&cur[dl], 1);
                csr[p] = src[e];
            }
        }
    }
}

// ------------------- gather layer 1 + bias + relu + @W2 (fused, 4 lanes/v) --
__global__ void k_gather1(const float* __restrict__ h1, const int* __restrict__ csr_src,
                          const int* __restrict__ off, const float* __restrict__ dinv,
                          const float* __restrict__ b1, const float* __restrict__ W2,
                          float* __restrict__ h2, int n) {
    int t = blockIdx.x * blockDim.x + threadIdx.x;
    int v = t >> 2, part = t & 3;
    if (v >= n) return;
    float di = dinv[v];
    float4 hv = reinterpret_cast<const float4*>(h1 + (size_t)v * HID)[part];
    float dw = di * di;
    float4 acc = make_float4(hv.x * dw, hv.y * dw, hv.z * dw, hv.w * dw);
    int beg = off[v], end = off[v + 1];
    for (int i = beg; i < end; ++i) {
        int s = csr_src[i];
        float w = dinv[s] * di;
        float4 hs = reinterpret_cast<const float4*>(h1 + (size_t)s * HID)[part];
        acc.x = fmaf(hs.x, w, acc.x);
        acc.y = fmaf(hs.y, w, acc.y);
        acc.z = fmaf(hs.z, w, acc.z);
        acc.w = fmaf(hs.w, w, acc.w);
    }
    float tt[4];
    tt[0] = fmaxf(acc.x + b1[part * 4 + 0], 0.0f);
    tt[1] = fmaxf(acc.y + b1[part * 4 + 1], 0.0f);
    tt[2] = fmaxf(acc.z + b1[part * 4 + 2], 0.0f);
    tt[3] = fmaxf(acc.w + b1[part * 4 + 3], 0.0f);
    float o[NC];
#pragma unroll
    for (int c = 0; c < NC; ++c) o[c] = 0.0f;
#pragma unroll
    for (int j = 0; j < 4; ++j) {
        int k = part * 4 + j;
#pragma unroll
        for (int c = 0; c < NC; ++c) o[c] = fmaf(tt[j], W2[k * NC + c], o[c]);
    }
#pragma unroll
    for (int c = 0; c < NC; ++c) {
        o[c] += __shfl_xor(o[c], 1);
        o[c] += __shfl_xor(o[c], 2);
    }
    float4* hp = reinterpret_cast<float4*>(h2 + (size_t)v * 8);
    if (part == 0) hp[0] = make_float4(o[0], o[1], o[2], o[3]);
    if (part == 1) hp[1] = make_float4(o[4], o[5], o[6], 0.0f);
}

// ------------------- gather layer 2 + bias + log_softmax (fused, 1 th/v) ----
__global__ void k_gather2(const float* __restrict__ h2, const int* __restrict__ csr_src,
                          const int* __restrict__ off, const float* __restrict__ dinv,
                          const float* __restrict__ b2, float* __restrict__ out, int n) {
    int v = blockIdx.x * blockDim.x + threadIdx.x;
    if (v >= n) return;
    float di = dinv[v];
    float dw = di * di;
    const float4* hr = reinterpret_cast<const float4*>(h2 + (size_t)v * 8);
    float4 s0 = hr[0], s1 = hr[1];
    float4 a0 = make_float4(s0.x * dw, s0.y * dw, s0.z * dw, s0.w * dw);
    float4 a1 = make_float4(s1.x * dw, s1.y * dw, s1.z * dw, 0.0f);
    int beg = off[v], end = off[v + 1];
    for (int i = beg; i < end; ++i) {
        int s = csr_src[i];
        float w = dinv[s] * di;
        const float4* hs = reinterpret_cast<const float4*>(h2 + (size_t)s * 8);
        float4 v0 = hs[0], v1 = hs[1];
        a0.x = fmaf(v0.x, w, a0.x);
        a0.y = fmaf(v0.y, w, a0.y);
        a0.z = fmaf(v0.z, w, a0.z);
        a0.w = fmaf(v0.w, w, a0.w);
        a1.x = fmaf(v1.x, w, a1.x);
        a1.y = fmaf(v1.y, w, a1.y);
        a1.z = fmaf(v1.z, w, a1.z);
    }
    float z[NC];
    z[0] = a0.x + b2[0]; z[1] = a0.y + b2[1]; z[2] = a0.z + b2[2]; z[3] = a0.w + b2[3];
    z[4] = a1.x + b2[4]; z[5] = a1.y + b2[5]; z[6] = a1.z + b2[6];
    float m = z[0];
#pragma unroll
    for (int c = 1; c < NC; ++c) m = fmaxf(m, z[c]);
    float sum = 0.0f;
#pragma unroll
    for (int c = 0; c < NC; ++c) sum += expf(z[c] - m);
    float lse = logf(sum) + m;
#pragma unroll
    for (int c = 0; c < NC; ++c) out[(size_t)v * NC + c] = z[c] - lse;
}

// -----------------------------------------------------------------------------
extern "C" void kernel_launch(void* const* d_in, const int* in_sizes, int n_in,
                              void* d_out, int out_size, void* d_ws, size_t ws_size,
                              hipStream_t stream) {
    const float* x  = (const float*)d_in[0];
    const int*   ei = (const int*)d_in[1];
    const float* W1 = (const float*)d_in[2];
    const float* b1 = (const float*)d_in[3];
    const float* W2 = (const float*)d_in[4];
    const float* b2 = (const float*)d_in[5];

    int n = in_sizes[0] / IN_FEAT;
    int E = in_sizes[1] / 2;
    const int* src = ei;
    const int* dst = ei + E;
    int NB = (n + NPB - 1) >> NPB_SH;

    // ws layout. NOTE: h1 no longer aliases binned (live concurrently in k_binmm).
    char* p = (char*)d_ws;
    int*   binned  = (int*)p;     p += (size_t)NB * CAPB * sizeof(int);  // 16.0 MB
    float* h1      = (float*)p;   p += (size_t)HID * n * sizeof(float);  // 6.4 MB
    float* h2      = (float*)p;   p += (size_t)8 * n * sizeof(float);    // 3.2 MB
    int*   csr_src = (int*)p;     p += (size_t)E * sizeof(int);          // 12.8 MB
    int*   gcur    = (int*)p;     p += (size_t)NBMAX * sizeof(int);
    int*   off     = (int*)p;     p += (size_t)(n + 1) * sizeof(int);
    float* dinv    = (float*)p;   p += (size_t)n * sizeof(float);

    const int tb = 256;
    int gN = (n + tb - 1) / tb;
    int gN4 = (4 * n + tb - 1) / tb;
    int nchunk = (E + P1_EDGES - 1) / P1_EDGES;

    hipMemsetAsync(gcur, 0, (size_t)NBMAX * sizeof(int), stream);
    k_binmm  <<<nchunk + gN, tb, 0, stream>>>(src, dst, gcur, binned, x, W1, h1,
                                              E, NB, nchunk, n);
    k_sort2  <<<NB, tb, 0, stream>>>(binned, gcur, off, dinv, csr_src,
                                     src, dst, n, E, NB);
    k_gather1<<<gN4, tb, 0, stream>>>(h1, csr_src, off, dinv, b1, W2, h2, n);
    k_gather2<<<gN,  tb, 0, stream>>>(h2, csr_src, off, dinv, b2, (float*)d_out, n);
}